// Round 7
// baseline (98.059 us; speedup 1.0000x reference)
//
#include <hip/hip_runtime.h>
#include <hip/hip_bf16.h>
#include <stdint.h>

// BatchHardTripletLoss: N=4096, D=512, C=128, margin=0.3
// hardest-pos = min gram (same label, j!=i), hardest-neg = max gram (diff label).
// Gram symmetric => upper-triangular 128x128 tiles (528 blocks).
//
// R7: gram switches to the T3-minimum 2-phase LDS pipeline (the one verified
// overlap structure not yet tried here):
//   prologue: STAGE(buf0, s=0); barrier;
//   step s:   STAGE(buf^1, s+1)  [8x global_load_lds/wave, in flight]
//             ds_read buf (16x b128/wave) + 32 MFMA  [covers fetch latency]
//             __syncthreads  [single drain per step]
// Rationale: R2/R5/R6 falsified the VGPR prefetch ring (compiler sinks loads,
// VGPR_Count=64); R1 FETCH=16.6MB=4x Ebf shows per-XCD L2-miss refetch at
// L3-class latency each step. LDS staging has no VGPR pressure; stage-before-
// compute ordering hides fetch under MFMA (baseline staged-then-drained with
// zero overlap). BK=64 dbuf = 64KB LDS -> 2 blocks/CU.
//
// Ebf swizzled layout (16B units): off16(row, kchunk) = (kchunk/4)*16384
//   + (row/16)*64 + (kchunk&3)*16 + (row&15)
// => 1KB chunk (ktile,rtile) is lane-contiguous; global_load_lds of a chunk
// lands in LDS already fragment-ordered (lds[chunk][lane] = frag data).

#define NROW 4096
#define DIM  512
#define MARGIN 0.3f
#define BT 128
#define NTILE (NROW / BT)                 // 32
#define NPAIR (NTILE * (NTILE + 1) / 2)   // 528
#define POS_INIT 0xFFFFFFFFu
#define NEG_INIT 0u

typedef __attribute__((ext_vector_type(8))) __bf16 bf16x8;
typedef __attribute__((ext_vector_type(4))) float  f32x4;
typedef __attribute__((ext_vector_type(8))) unsigned short u16x8;

// monotone float<->uint: order-preserving for atomicMin/Max on unsigned.
// enc(finite f) never equals POS_INIT (needs NaN) nor NEG_INIT (needs -NaN),
// so the init sentinels double as "no positive/negative seen" flags.
__device__ __forceinline__ unsigned enc(float f) {
    unsigned u = __float_as_uint(f);
    return (u & 0x80000000u) ? ~u : (u | 0x80000000u);
}
__device__ __forceinline__ float dec(unsigned e) {
    return (e & 0x80000000u) ? __uint_as_float(e & 0x7fffffffu)
                             : __uint_as_float(~e);
}

__device__ __forceinline__ unsigned short f2bf(float f) {
    __hip_bfloat16 h = __float2bfloat16(f);
    return *reinterpret_cast<unsigned short*>(&h);
}

__device__ __forceinline__ void async_copy16(const void* g, void* l) {
    __builtin_amdgcn_global_load_lds(
        (const __attribute__((address_space(1))) unsigned int*)g,
        (__attribute__((address_space(3))) unsigned int*)l,
        16, 0, 0);
}

// ---- kernel 1: L2-normalize rows -> bf16 swizzled layout, + init arrays ----
// 256 blocks x 256 thr; block b = rtile b (16 rows). Wave w: rows w*4..+3;
// lane = (r2=lane>>4, kc=lane&15); lane owns k in [kc*32, kc*32+32) -> ktile
// kc, c_in 0..3 -> 4 stores, 64B-granular across the 4-lane r2 groups.
__global__ void tl_norm(const float* __restrict__ E,
                        __hip_bfloat16* __restrict__ Ebf,
                        unsigned* __restrict__ posArr,
                        unsigned* __restrict__ negArr) {
    if (blockIdx.x < 16) {
        int t = blockIdx.x * 256 + threadIdx.x;   // covers 4096
        posArr[t] = POS_INIT;
        negArr[t] = NEG_INIT;
    }
    const int wave  = threadIdx.x >> 6;
    const int lane  = threadIdx.x & 63;
    const int r2    = lane >> 4;        // 0..3
    const int kc    = lane & 15;        // k-chunk-of-32
    const int rtile = blockIdx.x;       // 0..255
    const int r_in  = wave * 4 + r2;    // 0..15
    const int row   = rtile * 16 + r_in;

    const float4* src = (const float4*)(E + (size_t)row * DIM) + kc * 8;
    float4 v[8];
    #pragma unroll
    for (int i = 0; i < 8; i++) v[i] = src[i];

    float ss = 0.0f;
    #pragma unroll
    for (int i = 0; i < 8; i++)
        ss += v[i].x*v[i].x + v[i].y*v[i].y + v[i].z*v[i].z + v[i].w*v[i].w;
    // reduce across the 16 lanes sharing this row (r2 group preserved, m<16)
    #pragma unroll
    for (int m = 1; m < 16; m <<= 1) ss += __shfl_xor(ss, m);
    const float inv = 1.0f / fmaxf(sqrtf(ss), 1e-12f);

    u16x8* dst = (u16x8*)Ebf + (size_t)kc * 16384 + (size_t)rtile * 64 + r_in;
    #pragma unroll
    for (int c = 0; c < 4; c++) {
        const float4 lo = v[2*c], hi = v[2*c + 1];
        u16x8 o;
        o[0] = f2bf(lo.x * inv); o[1] = f2bf(lo.y * inv);
        o[2] = f2bf(lo.z * inv); o[3] = f2bf(lo.w * inv);
        o[4] = f2bf(hi.x * inv); o[5] = f2bf(hi.y * inv);
        o[6] = f2bf(hi.z * inv); o[7] = f2bf(hi.w * inv);
        dst[c * 16] = o;
    }
}

// ---- kernel 2: upper-tri bf16 MFMA Gram, 2-phase LDS pipeline ----
// 528 blocks x 256 thr (4 waves 2x2; wave-tile 64x64). BK=64 per step,
// double-buffered 64KB LDS. Per step/wave: 8x global_load_lds (next),
// 16x ds_read_b128 + 32 MFMA (current), one __syncthreads.
__global__ void __launch_bounds__(256, 2)
tl_gram(const __hip_bfloat16* __restrict__ Ebf,
        const int* __restrict__ labels,
        unsigned* __restrict__ posArr,
        unsigned* __restrict__ negArr) {
    __shared__ uint4 ldsAB[2][32][64];   // [buf][chunk][lane] = 64 KB
    __shared__ int rowLab[BT];
    __shared__ int colLab[BT];

    // bijective XCD swizzle: 528 = 8 * 66; consecutive swz ids (same bi ->
    // shared A panel) land on the same XCD's L2.
    const int bid = blockIdx.x;
    int t = (bid & 7) * (NPAIR / 8) + (bid >> 3);

    // triangular decode: t -> (bi, bj), bi <= bj
    int bi = 0, rowlen = NTILE;
    while (t >= rowlen) { t -= rowlen; rowlen--; bi++; }
    const int bj = bi + t;

    const int tid  = threadIdx.x;
    const int wave = tid >> 6;
    const int lane = tid & 63;
    const int quad = lane >> 4;
    const int l16  = lane & 15;
    const int wr   = wave >> 1;   // 0..1: rows wr*64..+63
    const int wc   = wave & 1;    // 0..1: cols wc*64..+63
    const int tileI = bi * BT;
    const int tileJ = bj * BT;
    const bool diag = (bi == bj);

    if (tid < BT) rowLab[tid] = labels[tileI + tid];
    else          colLab[tid - BT] = labels[tileJ + (tid - BT)];

    const int rtI0 = tileI >> 4;
    const int rtJ0 = tileJ >> 4;
    const uint4* Ev = (const uint4*)Ebf;

    // chunk ca in [0,32): ca<16 -> A (kl=ca>>3, rt=ca&7); ca>=16 -> B.
    // wave w stages ca = w*8 .. w*8+7 (waves 0,1: A; waves 2,3: B).
    auto stage = [&](int nbuf, int s) {
        const int kkBase = 2 * s;
        #pragma unroll
        for (int q = 0; q < 8; ++q) {
            const int ca  = wave * 8 + q;
            const int cc  = ca & 15;
            const int kl  = cc >> 3;
            const int rt  = cc & 7;
            const int rt0 = (ca >= 16) ? rtJ0 : rtI0;
            const uint4* src = Ev + (size_t)(kkBase + kl) * 16384
                                  + (size_t)(rt0 + rt) * 64 + lane;
            async_copy16(src, &ldsAB[nbuf][ca][0]);
        }
    };

    f32x4 acc[4][4] = {};

    stage(0, 0);
    __syncthreads();   // drains stage-0 (and publishes labels)

    #pragma unroll
    for (int s = 0; s < 8; ++s) {          // 8 K-steps of 64
        const int cur = s & 1;
        if (s < 7) stage(cur ^ 1, s + 1);  // in flight across this compute
        #pragma unroll
        for (int kl = 0; kl < 2; ++kl) {
            bf16x8 af[4], bg[4];
            #pragma unroll
            for (int mi = 0; mi < 4; mi++)
                af[mi] = *(const bf16x8*)&ldsAB[cur][kl * 8 + wr * 4 + mi][lane];
            #pragma unroll
            for (int ni = 0; ni < 4; ni++)
                bg[ni] = *(const bf16x8*)&ldsAB[cur][16 + kl * 8 + wc * 4 + ni][lane];
            #pragma unroll
            for (int mi = 0; mi < 4; mi++)
                #pragma unroll
                for (int ni = 0; ni < 4; ni++)
                    acc[mi][ni] = __builtin_amdgcn_mfma_f32_16x16x32_bf16(
                        af[mi], bg[ni], acc[mi][ni], 0, 0, 0);
        }
        __syncthreads();   // one drain per step; next buf now ready
    }

    // C/D layout: col = wc*64+ni*16+l16 (lane), row = wr*64+mi*16+quad*4+reg
    int rl[16], cl[4], clocv[4];
    #pragma unroll
    for (int mi = 0; mi < 4; mi++)
        #pragma unroll
        for (int reg = 0; reg < 4; reg++)
            rl[mi * 4 + reg] = rowLab[wr * 64 + mi * 16 + quad * 4 + reg];
    #pragma unroll
    for (int ni = 0; ni < 4; ni++) {
        clocv[ni] = wc * 64 + ni * 16 + l16;
        cl[ni] = colLab[clocv[ni]];
    }

    // ---- row pass: reduce over this wave's 64 cols, rows of tileI ----
    #pragma unroll
    for (int mi = 0; mi < 4; mi++) {
        #pragma unroll
        for (int reg = 0; reg < 4; reg++) {
            const int rloc = wr * 64 + mi * 16 + quad * 4 + reg;
            const int lr   = rl[mi * 4 + reg];
            const int gi   = tileI + rloc;
            float pmin =  INFINITY;
            float nmax = -INFINITY;
            #pragma unroll
            for (int ni = 0; ni < 4; ni++) {
                const int gj  = tileJ + clocv[ni];
                const float g = acc[mi][ni][reg];
                const bool same = (lr == cl[ni]);
                if (same && gi != gj) pmin = fminf(pmin, g);
                if (!same)            nmax = fmaxf(nmax, g);
            }
            #pragma unroll
            for (int m = 1; m < 16; m <<= 1) {
                pmin = fminf(pmin, __shfl_xor(pmin, m));
                nmax = fmaxf(nmax, __shfl_xor(nmax, m));
            }
            if (l16 == 0) {
                if (pmin <  INFINITY) atomicMin(&posArr[gi], enc(pmin));
                if (nmax > -INFINITY) atomicMax(&negArr[gi], enc(nmax));
            }
        }
    }

    // ---- col pass (off-diag only): reduce over this wave's 64 rows ----
    if (!diag) {
        #pragma unroll
        for (int ni = 0; ni < 4; ni++) {
            const int lc = cl[ni];
            const int gj = tileJ + clocv[ni];
            float pmin =  INFINITY;
            float nmax = -INFINITY;
            #pragma unroll
            for (int mi = 0; mi < 4; mi++) {
                #pragma unroll
                for (int reg = 0; reg < 4; reg++) {
                    const float g = acc[mi][ni][reg];
                    const bool same = (rl[mi * 4 + reg] == lc);
                    if (same) pmin = fminf(pmin, g);
                    else      nmax = fmaxf(nmax, g);
                }
            }
            pmin = fminf(pmin, __shfl_xor(pmin, 16));
            pmin = fminf(pmin, __shfl_xor(pmin, 32));
            nmax = fmaxf(nmax, __shfl_xor(nmax, 16));
            nmax = fmaxf(nmax, __shfl_xor(nmax, 32));
            if (quad == 0) {
                if (pmin <  INFINITY) atomicMin(&posArr[gj], enc(pmin));
                if (nmax > -INFINITY) atomicMax(&negArr[gj], enc(nmax));
            }
        }
    }
}

// ---- kernel 3: per-row loss + mean over valid rows ----
__global__ void tl_final(const unsigned* __restrict__ posArr,
                         const unsigned* __restrict__ negArr,
                         float* __restrict__ out) {
    const int tid = threadIdx.x; // 1024 threads, 4 rows each, single pass
    uint4 pe4 = ((const uint4*)posArr)[tid];
    uint4 ne4 = ((const uint4*)negArr)[tid];
    unsigned pes[4] = {pe4.x, pe4.y, pe4.z, pe4.w};
    unsigned nes[4] = {ne4.x, ne4.y, ne4.z, ne4.w};
    float sum = 0.0f;
    int   count = 0;
    #pragma unroll
    for (int j = 0; j < 4; j++) {
        const bool valid = (pes[j] != POS_INIT) && (nes[j] != NEG_INIT);
        const float dap = sqrtf(fmaxf(2.0f - 2.0f * dec(pes[j]), 0.0f));
        const float dan = sqrtf(fmaxf(2.0f - 2.0f * dec(nes[j]), 0.0f));
        const float per = fmaxf(dap - dan + MARGIN, 0.0f);
        if (valid) { sum += per; count += 1; }
    }
    #pragma unroll
    for (int m = 32; m >= 1; m >>= 1) {
        sum   += __shfl_xor(sum, m);
        count += __shfl_xor(count, m);
    }
    __shared__ float ssum[16];
    __shared__ int   scnt[16];
    const int wave = tid >> 6, lane = tid & 63;
    if (lane == 0) { ssum[wave] = sum; scnt[wave] = count; }
    __syncthreads();
    if (tid == 0) {
        float s = 0.0f; int c = 0;
        #pragma unroll
        for (int w = 0; w < 16; w++) { s += ssum[w]; c += scnt[w]; }
        out[0] = (c > 0) ? (s / (float)c) : 0.0f;
    }
}

extern "C" void kernel_launch(void* const* d_in, const int* in_sizes, int n_in,
                              void* d_out, int out_size, void* d_ws, size_t ws_size,
                              hipStream_t stream) {
    const float* E      = (const float*)d_in[0];
    const int*   labels = (const int*)d_in[1];
    float*       out    = (float*)d_out;

    char* ws = (char*)d_ws;
    __hip_bfloat16* Ebf   = (__hip_bfloat16*)ws;                       // 4 MB
    unsigned* posArr      = (unsigned*)(ws + (size_t)NROW * DIM * 2);  // 16 KB
    unsigned* negArr      = posArr + NROW;                             // 16 KB

    tl_norm<<<NROW / 16, 256, 0, stream>>>(E, Ebf, posArr, negArr);
    tl_gram<<<NPAIR, 256, 0, stream>>>(Ebf, labels, posArr, negArr);
    tl_final<<<1, 1024, 0, stream>>>(posArr, negArr, out);
}

// Round 8
// 94.975 us; speedup vs baseline: 1.0325x; 1.0325x over previous
//
#include <hip/hip_runtime.h>
#include <hip/hip_bf16.h>
#include <stdint.h>

// BatchHardTripletLoss: N=4096, D=512, C=128, margin=0.3
// hardest-pos = min gram (same label, j!=i), hardest-neg = max gram (diff label).
// Gram symmetric => upper-triangular 128x128 tiles (528 blocks).
//
// R8 = R2 structure (best measured: free-running direct-L2 swizzled frags,
// zero K-loop barriers) + the AITER mechanism for the in-flight wall:
// inline-asm global_load_dwordx4 (compiler cannot sink or auto-wait them) +
// counted s_waitcnt vmcnt(24/16/8/0) ladder + sched_barrier(0) after each
// wait (rule #18: stops MFMA hoisting past the asm wait). Evidence: R2's
// VGPR_Count=64 => compiler collapsed the ring to ~2 loads in flight/wave;
// 2KB*8waves/700cy ~= 15-23 B/cy/CU == measured service. Ladder keeps 24-32
// loads (24-32KB) in flight per wave. Barrier-stepped LDS variants (R7: 37.6us)
// and sched_barrier pinning (R6: 32us) both lost to R2 (28.7us); this attacks
// R2's actual limiter.
//
// Ebf swizzled layout (16B units): off16(row, kchunk) = (kchunk/4)*16384
//   + (row/16)*64 + (kchunk&3)*16 + (row&15)
// => fragment (16 rows x 32 k) load = one contiguous 1KB wave load;
//    frag i at byte offset i*1024 within a step, step stride 262144 B.

#define NROW 4096
#define DIM  512
#define MARGIN 0.3f
#define BT 128
#define NTILE (NROW / BT)                 // 32
#define NPAIR (NTILE * (NTILE + 1) / 2)   // 528
#define POS_INIT 0xFFFFFFFFu
#define NEG_INIT 0u

typedef __attribute__((ext_vector_type(8))) __bf16 bf16x8;
typedef __attribute__((ext_vector_type(4))) float  f32x4;
typedef __attribute__((ext_vector_type(8))) unsigned short u16x8;

// monotone float<->uint: order-preserving for atomicMin/Max on unsigned.
// enc(finite f) never equals POS_INIT (needs NaN) nor NEG_INIT (needs -NaN),
// so the init sentinels double as "no positive/negative seen" flags.
__device__ __forceinline__ unsigned enc(float f) {
    unsigned u = __float_as_uint(f);
    return (u & 0x80000000u) ? ~u : (u | 0x80000000u);
}
__device__ __forceinline__ float dec(unsigned e) {
    return (e & 0x80000000u) ? __uint_as_float(e & 0x7fffffffu)
                             : __uint_as_float(~e);
}

__device__ __forceinline__ unsigned short f2bf(float f) {
    __hip_bfloat16 h = __float2bfloat16(f);
    return *reinterpret_cast<unsigned short*>(&h);
}

// ---- kernel 1: L2-normalize rows -> bf16 swizzled layout, + init arrays ----
__global__ void tl_norm(const float* __restrict__ E,
                        __hip_bfloat16* __restrict__ Ebf,
                        unsigned* __restrict__ posArr,
                        unsigned* __restrict__ negArr) {
    if (blockIdx.x < 16) {
        int t = blockIdx.x * 256 + threadIdx.x;   // covers 4096
        posArr[t] = POS_INIT;
        negArr[t] = NEG_INIT;
    }
    const int wave  = threadIdx.x >> 6;
    const int lane  = threadIdx.x & 63;
    const int r2    = lane >> 4;        // 0..3
    const int kc    = lane & 15;        // k-chunk-of-32
    const int rtile = blockIdx.x;       // 0..255
    const int r_in  = wave * 4 + r2;    // 0..15
    const int row   = rtile * 16 + r_in;

    const float4* src = (const float4*)(E + (size_t)row * DIM) + kc * 8;
    float4 v[8];
    #pragma unroll
    for (int i = 0; i < 8; i++) v[i] = src[i];

    float ss = 0.0f;
    #pragma unroll
    for (int i = 0; i < 8; i++)
        ss += v[i].x*v[i].x + v[i].y*v[i].y + v[i].z*v[i].z + v[i].w*v[i].w;
    #pragma unroll
    for (int m = 1; m < 16; m <<= 1) ss += __shfl_xor(ss, m);
    const float inv = 1.0f / fmaxf(sqrtf(ss), 1e-12f);

    u16x8* dst = (u16x8*)Ebf + (size_t)kc * 16384 + (size_t)rtile * 64 + r_in;
    #pragma unroll
    for (int c = 0; c < 4; c++) {
        const float4 lo = v[2*c], hi = v[2*c + 1];
        u16x8 o;
        o[0] = f2bf(lo.x * inv); o[1] = f2bf(lo.y * inv);
        o[2] = f2bf(lo.z * inv); o[3] = f2bf(lo.w * inv);
        o[4] = f2bf(hi.x * inv); o[5] = f2bf(hi.y * inv);
        o[6] = f2bf(hi.z * inv); o[7] = f2bf(hi.w * inv);
        dst[c * 16] = o;
    }
}

// issue 8 x 1KB fragment loads (4 A + 4 B) for K-step kkq into ring slot `sl`.
// asm volatile: unsinkable, no compiler auto-waitcnt on the results.
#define ISSUE8(sl, kkq) do {                                                  \
    const uint4* _pa = EaU + (size_t)(kkq) * 16384;                           \
    const uint4* _pb = EbU + (size_t)(kkq) * 16384;                           \
    asm volatile(                                                             \
        "global_load_dwordx4 %0, %8, off\n\t"                                 \
        "global_load_dwordx4 %1, %8, off offset:1024\n\t"                     \
        "global_load_dwordx4 %2, %8, off offset:2048\n\t"                     \
        "global_load_dwordx4 %3, %8, off offset:3072\n\t"                     \
        "global_load_dwordx4 %4, %9, off\n\t"                                 \
        "global_load_dwordx4 %5, %9, off offset:1024\n\t"                     \
        "global_load_dwordx4 %6, %9, off offset:2048\n\t"                     \
        "global_load_dwordx4 %7, %9, off offset:3072"                         \
        : "=&v"(a[sl][0]), "=&v"(a[sl][1]), "=&v"(a[sl][2]), "=&v"(a[sl][3]), \
          "=&v"(b[sl][0]), "=&v"(b[sl][1]), "=&v"(b[sl][2]), "=&v"(b[sl][3])  \
        : "v"(_pa), "v"(_pb));                                                \
} while (0)

// counted wait + scheduling fence (rule #18: MFMA must not hoist past it)
#define WAITV(n) do {                                                         \
    asm volatile("s_waitcnt vmcnt(" #n ")" ::: "memory");                     \
    __builtin_amdgcn_sched_barrier(0);                                        \
} while (0)

#define MFMA16(sl) do {                                                       \
    _Pragma("unroll")                                                         \
    for (int mi = 0; mi < 4; mi++)                                            \
        _Pragma("unroll")                                                     \
        for (int ni = 0; ni < 4; ni++)                                        \
            acc[mi][ni] = __builtin_amdgcn_mfma_f32_16x16x32_bf16(            \
                a[sl][mi], b[sl][ni], acc[mi][ni], 0, 0, 0);                  \
} while (0)

// ---- kernel 2: upper-tri bf16 MFMA Gram, counted-vmcnt deep pipeline ----
// 528 blocks x 256 thr (4 waves 2x2; wave-tile 64x64). Ring-4 register
// prefetch held open by the asm ladder: steady state 24-32 loads in flight.
__global__ void __launch_bounds__(256, 2)
tl_gram(const __hip_bfloat16* __restrict__ Ebf,
        const int* __restrict__ labels,
        unsigned* __restrict__ posArr,
        unsigned* __restrict__ negArr) {
    __shared__ int rowLab[BT];
    __shared__ int colLab[BT];

    // bijective XCD swizzle: 528 = 8 * 66
    const int bid = blockIdx.x;
    int t = (bid & 7) * (NPAIR / 8) + (bid >> 3);

    // triangular decode: t -> (bi, bj), bi <= bj
    int bi = 0, rowlen = NTILE;
    while (t >= rowlen) { t -= rowlen; rowlen--; bi++; }
    const int bj = bi + t;

    const int tid  = threadIdx.x;
    const int wave = tid >> 6;
    const int lane = tid & 63;
    const int quad = lane >> 4;
    const int l16  = lane & 15;
    const int wr   = wave >> 1;   // 0..1: rows wr*64..+63
    const int wc   = wave & 1;    // 0..1: cols wc*64..+63
    const int tileI = bi * BT;
    const int tileJ = bj * BT;
    const bool diag = (bi == bj);

    if (tid < BT) rowLab[tid] = labels[tileI + tid];
    else          colLab[tid - BT] = labels[tileJ + (tid - BT)];
    __syncthreads();   // drains label loads: vmcnt == 0 entering the K-loop

    // swizzled fragment base (16B units): kk*16384 + (rowbase/16)*64 + lane
    const uint4* Ev  = (const uint4*)Ebf;
    const uint4* EaU = Ev + ((tileI + wr * 64) >> 4) * 64 + lane;
    const uint4* EbU = Ev + ((tileJ + wc * 64) >> 4) * 64 + lane;

    f32x4 acc[4][4] = {};
    bf16x8 a[4][4], b[4][4];   // ring slot x frag, all indices compile-time

    // prologue: 3 steps deep (24 loads in flight)
    ISSUE8(0, 0); ISSUE8(1, 1); ISSUE8(2, 2);

    // steady state: issue step kk+3, wait for step kk (24 = 3 steps x 8 still
    // outstanding), compute step kk. Epilogue ladder 16/8/0.
    ISSUE8(3, 3);   WAITV(24); MFMA16(0);   // kk = 0
    ISSUE8(0, 4);   WAITV(24); MFMA16(1);   // kk = 1
    ISSUE8(1, 5);   WAITV(24); MFMA16(2);   // kk = 2
    ISSUE8(2, 6);   WAITV(24); MFMA16(3);   // kk = 3
    ISSUE8(3, 7);   WAITV(24); MFMA16(0);   // kk = 4
    ISSUE8(0, 8);   WAITV(24); MFMA16(1);   // kk = 5
    ISSUE8(1, 9);   WAITV(24); MFMA16(2);   // kk = 6
    ISSUE8(2, 10);  WAITV(24); MFMA16(3);   // kk = 7
    ISSUE8(3, 11);  WAITV(24); MFMA16(0);   // kk = 8
    ISSUE8(0, 12);  WAITV(24); MFMA16(1);   // kk = 9
    ISSUE8(1, 13);  WAITV(24); MFMA16(2);   // kk = 10
    ISSUE8(2, 14);  WAITV(24); MFMA16(3);   // kk = 11
    ISSUE8(3, 15);  WAITV(24); MFMA16(0);   // kk = 12
                    WAITV(16); MFMA16(1);   // kk = 13
                    WAITV(8);  MFMA16(2);   // kk = 14
                    WAITV(0);  MFMA16(3);   // kk = 15

    // C/D layout: col = wc*64+ni*16+l16 (lane), row = wr*64+mi*16+quad*4+reg
    int rl[16], cl[4], clocv[4];
    #pragma unroll
    for (int mi = 0; mi < 4; mi++)
        #pragma unroll
        for (int reg = 0; reg < 4; reg++)
            rl[mi * 4 + reg] = rowLab[wr * 64 + mi * 16 + quad * 4 + reg];
    #pragma unroll
    for (int ni = 0; ni < 4; ni++) {
        clocv[ni] = wc * 64 + ni * 16 + l16;
        cl[ni] = colLab[clocv[ni]];
    }

    // ---- row pass: reduce over this wave's 64 cols, rows of tileI ----
    #pragma unroll
    for (int mi = 0; mi < 4; mi++) {
        #pragma unroll
        for (int reg = 0; reg < 4; reg++) {
            const int rloc = wr * 64 + mi * 16 + quad * 4 + reg;
            const int lr   = rl[mi * 4 + reg];
            const int gi   = tileI + rloc;
            float pmin =  INFINITY;
            float nmax = -INFINITY;
            #pragma unroll
            for (int ni = 0; ni < 4; ni++) {
                const int gj  = tileJ + clocv[ni];
                const float g = acc[mi][ni][reg];
                const bool same = (lr == cl[ni]);
                if (same && gi != gj) pmin = fminf(pmin, g);
                if (!same)            nmax = fmaxf(nmax, g);
            }
            #pragma unroll
            for (int m = 1; m < 16; m <<= 1) {
                pmin = fminf(pmin, __shfl_xor(pmin, m));
                nmax = fmaxf(nmax, __shfl_xor(nmax, m));
            }
            if (l16 == 0) {
                if (pmin <  INFINITY) atomicMin(&posArr[gi], enc(pmin));
                if (nmax > -INFINITY) atomicMax(&negArr[gi], enc(nmax));
            }
        }
    }

    // ---- col pass (off-diag only): reduce over this wave's 64 rows ----
    if (!diag) {
        #pragma unroll
        for (int ni = 0; ni < 4; ni++) {
            const int lc = cl[ni];
            const int gj = tileJ + clocv[ni];
            float pmin =  INFINITY;
            float nmax = -INFINITY;
            #pragma unroll
            for (int mi = 0; mi < 4; mi++) {
                #pragma unroll
                for (int reg = 0; reg < 4; reg++) {
                    const float g = acc[mi][ni][reg];
                    const bool same = (rl[mi * 4 + reg] == lc);
                    if (same) pmin = fminf(pmin, g);
                    else      nmax = fmaxf(nmax, g);
                }
            }
            pmin = fminf(pmin, __shfl_xor(pmin, 16));
            pmin = fminf(pmin, __shfl_xor(pmin, 32));
            nmax = fmaxf(nmax, __shfl_xor(nmax, 16));
            nmax = fmaxf(nmax, __shfl_xor(nmax, 32));
            if (quad == 0) {
                if (pmin <  INFINITY) atomicMin(&posArr[gj], enc(pmin));
                if (nmax > -INFINITY) atomicMax(&negArr[gj], enc(nmax));
            }
        }
    }
}

// ---- kernel 3: per-row loss + mean over valid rows ----
__global__ void tl_final(const unsigned* __restrict__ posArr,
                         const unsigned* __restrict__ negArr,
                         float* __restrict__ out) {
    const int tid = threadIdx.x; // 1024 threads, 4 rows each, single pass
    uint4 pe4 = ((const uint4*)posArr)[tid];
    uint4 ne4 = ((const uint4*)negArr)[tid];
    unsigned pes[4] = {pe4.x, pe4.y, pe4.z, pe4.w};
    unsigned nes[4] = {ne4.x, ne4.y, ne4.z, ne4.w};
    float sum = 0.0f;
    int   count = 0;
    #pragma unroll
    for (int j = 0; j < 4; j++) {
        const bool valid = (pes[j] != POS_INIT) && (nes[j] != NEG_INIT);
        const float dap = sqrtf(fmaxf(2.0f - 2.0f * dec(pes[j]), 0.0f));
        const float dan = sqrtf(fmaxf(2.0f - 2.0f * dec(nes[j]), 0.0f));
        const float per = fmaxf(dap - dan + MARGIN, 0.0f);
        if (valid) { sum += per; count += 1; }
    }
    #pragma unroll
    for (int m = 32; m >= 1; m >>= 1) {
        sum   += __shfl_xor(sum, m);
        count += __shfl_xor(count, m);
    }
    __shared__ float ssum[16];
    __shared__ int   scnt[16];
    const int wave = tid >> 6, lane = tid & 63;
    if (lane == 0) { ssum[wave] = sum; scnt[wave] = count; }
    __syncthreads();
    if (tid == 0) {
        float s = 0.0f; int c = 0;
        #pragma unroll
        for (int w = 0; w < 16; w++) { s += ssum[w]; c += scnt[w]; }
        out[0] = (c > 0) ? (s / (float)c) : 0.0f;
    }
}

extern "C" void kernel_launch(void* const* d_in, const int* in_sizes, int n_in,
                              void* d_out, int out_size, void* d_ws, size_t ws_size,
                              hipStream_t stream) {
    const float* E      = (const float*)d_in[0];
    const int*   labels = (const int*)d_in[1];
    float*       out    = (float*)d_out;

    char* ws = (char*)d_ws;
    __hip_bfloat16* Ebf   = (__hip_bfloat16*)ws;                       // 4 MB
    unsigned* posArr      = (unsigned*)(ws + (size_t)NROW * DIM * 2);  // 16 KB
    unsigned* negArr      = posArr + NROW;                             // 16 KB

    tl_norm<<<NROW / 16, 256, 0, stream>>>(E, Ebf, posArr, negArr);
    tl_gram<<<NPAIR, 256, 0, stream>>>(Ebf, labels, posArr, negArr);
    tl_final<<<1, 1024, 0, stream>>>(posArr, negArr, out);
}

// Round 9
// 93.125 us; speedup vs baseline: 1.0530x; 1.0199x over previous
//
#include <hip/hip_runtime.h>
#include <hip/hip_bf16.h>
#include <stdint.h>

// BatchHardTripletLoss: N=4096, D=512, C=128, margin=0.3
// hardest-pos = min gram (same label, j!=i), hardest-neg = max gram (diff label).
// Gram symmetric => upper-triangular 128x128 tiles (528 blocks).
//
// R9: traffic-reduction + drain-free pipeline (m201-template mechanism).
// Diagnosis across R2/R5-R8: limiter is 64B line-request service (~4.2 cyc/line
// /CU achieved vs ~0.5 ideal), and R2's per-wave direct-L2 loads fetch every
// panel TWICE per block (waves duplicate). Fix: stage each panel once per
// block into a 4-deep LDS ring via global_load_lds (halves line count), and
// keep loads in flight across steps with counted s_waitcnt vmcnt(12) + RAW
// s_barrier (no vmcnt(0) drain — R7's killer). ds_reads are inline asm so the
// compiler cannot see a gload_lds->ds_read dependency and auto-insert vmcnt(0);
// rule #18 fence (lgkmcnt(0)+sched_barrier) guards the MFMAs.
//
// Ebf swizzled layout (16B units): off16(row, kchunk) = (kchunk/4)*16384
//   + (row/16)*64 + (kchunk&3)*16 + (row&15)
// => step s (k in [32s,32s+32)) = ktile s; panel chunk (16 rows x 32 k) = 1KB
//    lane-contiguous; gload_lds lands it in LDS already fragment-ordered.

#define NROW 4096
#define DIM  512
#define MARGIN 0.3f
#define BT 128
#define NTILE (NROW / BT)                 // 32
#define NPAIR (NTILE * (NTILE + 1) / 2)   // 528
#define POS_INIT 0xFFFFFFFFu
#define NEG_INIT 0u

typedef __attribute__((ext_vector_type(8))) __bf16 bf16x8;
typedef __attribute__((ext_vector_type(4))) float  f32x4;
typedef __attribute__((ext_vector_type(8))) unsigned short u16x8;

__device__ __forceinline__ unsigned enc(float f) {
    unsigned u = __float_as_uint(f);
    return (u & 0x80000000u) ? ~u : (u | 0x80000000u);
}
__device__ __forceinline__ float dec(unsigned e) {
    return (e & 0x80000000u) ? __uint_as_float(e & 0x7fffffffu)
                             : __uint_as_float(~e);
}

__device__ __forceinline__ unsigned short f2bf(float f) {
    __hip_bfloat16 h = __float2bfloat16(f);
    return *reinterpret_cast<unsigned short*>(&h);
}

__device__ __forceinline__ void async_copy16(const void* g, void* l) {
    __builtin_amdgcn_global_load_lds(
        (const __attribute__((address_space(1))) unsigned int*)g,
        (__attribute__((address_space(3))) unsigned int*)l,
        16, 0, 0);
}

// ---- kernel 1: L2-normalize rows -> bf16 swizzled layout, + init arrays ----
__global__ void tl_norm(const float* __restrict__ E,
                        __hip_bfloat16* __restrict__ Ebf,
                        unsigned* __restrict__ posArr,
                        unsigned* __restrict__ negArr) {
    if (blockIdx.x < 16) {
        int t = blockIdx.x * 256 + threadIdx.x;   // covers 4096
        posArr[t] = POS_INIT;
        negArr[t] = NEG_INIT;
    }
    const int wave  = threadIdx.x >> 6;
    const int lane  = threadIdx.x & 63;
    const int r2    = lane >> 4;        // 0..3
    const int kc    = lane & 15;        // k-chunk-of-32
    const int rtile = blockIdx.x;       // 0..255
    const int r_in  = wave * 4 + r2;    // 0..15
    const int row   = rtile * 16 + r_in;

    const float4* src = (const float4*)(E + (size_t)row * DIM) + kc * 8;
    float4 v[8];
    #pragma unroll
    for (int i = 0; i < 8; i++) v[i] = src[i];

    float ss = 0.0f;
    #pragma unroll
    for (int i = 0; i < 8; i++)
        ss += v[i].x*v[i].x + v[i].y*v[i].y + v[i].z*v[i].z + v[i].w*v[i].w;
    #pragma unroll
    for (int m = 1; m < 16; m <<= 1) ss += __shfl_xor(ss, m);
    const float inv = 1.0f / fmaxf(sqrtf(ss), 1e-12f);

    u16x8* dst = (u16x8*)Ebf + (size_t)kc * 16384 + (size_t)rtile * 64 + r_in;
    #pragma unroll
    for (int c = 0; c < 4; c++) {
        const float4 lo = v[2*c], hi = v[2*c + 1];
        u16x8 o;
        o[0] = f2bf(lo.x * inv); o[1] = f2bf(lo.y * inv);
        o[2] = f2bf(lo.z * inv); o[3] = f2bf(lo.w * inv);
        o[4] = f2bf(hi.x * inv); o[5] = f2bf(hi.y * inv);
        o[6] = f2bf(hi.z * inv); o[7] = f2bf(hi.w * inv);
        dst[c * 16] = o;
    }
}

// stage step s into ring slot (s&3): wave w stages chunks w*4..w*4+3
// (chunks 0-7 = A rtiles 0-7; chunks 8-15 = B rtiles 0-7). 4 x gload_lds.
#define ISSUE(s) do {                                                         \
    if ((s) < 16) {                                                           \
        _Pragma("unroll")                                                     \
        for (int q = 0; q < 4; ++q) {                                         \
            const int c   = wave * 4 + q;                                     \
            const int rt0 = (c >= 8) ? rtJ0 : rtI0;                           \
            const int rt  = (c >= 8) ? c - 8 : c;                             \
            const uint4* src = Ev + (size_t)(s) * 16384                       \
                                  + (size_t)(rt0 + rt) * 64 + lane;           \
            async_copy16(src, &sbuf[(s) & 3][c][0]);                          \
        }                                                                     \
    }                                                                         \
} while (0)

// counted wait: own oldest stage complete; fence the codegen scheduler.
#define WAITV(n) do {                                                         \
    asm volatile("s_waitcnt vmcnt(" #n ")" ::: "memory");                     \
    __builtin_amdgcn_sched_barrier(0);                                        \
} while (0)

// opaque LDS read: compiler can't link it to gload_lds (no auto vmcnt(0)).
#define DSR(dst, addr) \
    asm volatile("ds_read_b128 %0, %1" : "=&v"(dst) : "v"(addr));

#define COMPUTE(s) do {                                                       \
    bf16x8 af[4], bg[4];                                                      \
    _Pragma("unroll")                                                         \
    for (int mi = 0; mi < 4; mi++)                                            \
        DSR(af[mi], vA + (unsigned)(((s) & 3) * 16384 + mi * 1024));          \
    _Pragma("unroll")                                                         \
    for (int ni = 0; ni < 4; ni++)                                            \
        DSR(bg[ni], vB + (unsigned)(((s) & 3) * 16384 + ni * 1024));          \
    asm volatile("s_waitcnt lgkmcnt(0)" ::: "memory");                        \
    __builtin_amdgcn_sched_barrier(0);                                        \
    _Pragma("unroll")                                                         \
    for (int mi = 0; mi < 4; mi++)                                            \
        _Pragma("unroll")                                                     \
        for (int ni = 0; ni < 4; ni++)                                        \
            acc[mi][ni] = __builtin_amdgcn_mfma_f32_16x16x32_bf16(            \
                af[mi], bg[ni], acc[mi][ni], 0, 0, 0);                        \
} while (0)

// step s: wait own stage-s done -> barrier (all waves' stage-s done) ->
// compute from slot s&3 -> barrier (reads done; slot may be rewritten) ->
// issue stage s+4 into slot s&3.
#define STEP(s, w) do {                                                       \
    WAITV(w);                                                                 \
    __builtin_amdgcn_s_barrier();                                             \
    COMPUTE(s);                                                               \
    __builtin_amdgcn_sched_barrier(0);                                        \
    __builtin_amdgcn_s_barrier();                                             \
    ISSUE((s) + 4);                                                           \
} while (0)

// ---- kernel 2: upper-tri bf16 MFMA Gram, LDS ring + counted vmcnt ----
// 528 blocks x 256 thr (4 waves 2x2; wave-tile 64x64). 4-deep 16KB ring.
__global__ void __launch_bounds__(256, 2)
tl_gram(const __hip_bfloat16* __restrict__ Ebf,
        const int* __restrict__ labels,
        unsigned* __restrict__ posArr,
        unsigned* __restrict__ negArr) {
    __shared__ uint4 sbuf[4][16][64];   // ring: [slot][chunk][lane16B] = 64 KB
    __shared__ int rowLab[BT];
    __shared__ int colLab[BT];

    // bijective XCD swizzle: 528 = 8 * 66
    const int bid = blockIdx.x;
    int t = (bid & 7) * (NPAIR / 8) + (bid >> 3);

    // triangular decode: t -> (bi, bj), bi <= bj
    int bi = 0, rowlen = NTILE;
    while (t >= rowlen) { t -= rowlen; rowlen--; bi++; }
    const int bj = bi + t;

    const int tid  = threadIdx.x;
    const int wave = tid >> 6;
    const int lane = tid & 63;
    const int quad = lane >> 4;
    const int l16  = lane & 15;
    const int wr   = wave >> 1;   // 0..1: rows wr*64..+63
    const int wc   = wave & 1;    // 0..1: cols wc*64..+63
    const int tileI = bi * BT;
    const int tileJ = bj * BT;
    const bool diag = (bi == bj);

    if (tid < BT) rowLab[tid] = labels[tileI + tid];
    else          colLab[tid - BT] = labels[tileJ + (tid - BT)];
    __syncthreads();   // drains label loads: vmcnt==0 entering the pipeline

    const int rtI0 = tileI >> 4;
    const int rtJ0 = tileJ >> 4;
    const uint4* Ev = (const uint4*)Ebf;

    // LDS byte addresses for this wave's fragment reads (asm ds_read)
    const uint32_t sbase =
        (uint32_t)(uintptr_t)(__attribute__((address_space(3))) void*)&sbuf[0][0][0];
    const uint32_t vA = sbase + (uint32_t)(wr * 4 * 1024) + (uint32_t)(lane * 16);
    const uint32_t vB = sbase + (uint32_t)((8 + wc * 4) * 1024) + (uint32_t)(lane * 16);

    f32x4 acc[4][4] = {};

    // prologue: fill the 4-slot ring (16 gload_lds in flight per wave)
    ISSUE(0); ISSUE(1); ISSUE(2); ISSUE(3);

    STEP(0, 12);  STEP(1, 12);  STEP(2, 12);  STEP(3, 12);
    STEP(4, 12);  STEP(5, 12);  STEP(6, 12);  STEP(7, 12);
    STEP(8, 12);  STEP(9, 12);  STEP(10, 12); STEP(11, 12);
    STEP(12, 12); STEP(13, 8);  STEP(14, 4);  STEP(15, 0);

    // C/D layout: col = wc*64+ni*16+l16 (lane), row = wr*64+mi*16+quad*4+reg
    int rl[16], cl[4], clocv[4];
    #pragma unroll
    for (int mi = 0; mi < 4; mi++)
        #pragma unroll
        for (int reg = 0; reg < 4; reg++)
            rl[mi * 4 + reg] = rowLab[wr * 64 + mi * 16 + quad * 4 + reg];
    #pragma unroll
    for (int ni = 0; ni < 4; ni++) {
        clocv[ni] = wc * 64 + ni * 16 + l16;
        cl[ni] = colLab[clocv[ni]];
    }

    // ---- row pass: reduce over this wave's 64 cols, rows of tileI ----
    #pragma unroll
    for (int mi = 0; mi < 4; mi++) {
        #pragma unroll
        for (int reg = 0; reg < 4; reg++) {
            const int rloc = wr * 64 + mi * 16 + quad * 4 + reg;
            const int lr   = rl[mi * 4 + reg];
            const int gi   = tileI + rloc;
            float pmin =  INFINITY;
            float nmax = -INFINITY;
            #pragma unroll
            for (int ni = 0; ni < 4; ni++) {
                const int gj  = tileJ + clocv[ni];
                const float g = acc[mi][ni][reg];
                const bool same = (lr == cl[ni]);
                if (same && gi != gj) pmin = fminf(pmin, g);
                if (!same)            nmax = fmaxf(nmax, g);
            }
            #pragma unroll
            for (int m = 1; m < 16; m <<= 1) {
                pmin = fminf(pmin, __shfl_xor(pmin, m));
                nmax = fmaxf(nmax, __shfl_xor(nmax, m));
            }
            if (l16 == 0) {
                if (pmin <  INFINITY) atomicMin(&posArr[gi], enc(pmin));
                if (nmax > -INFINITY) atomicMax(&negArr[gi], enc(nmax));
            }
        }
    }

    // ---- col pass (off-diag only): reduce over this wave's 64 rows ----
    if (!diag) {
        #pragma unroll
        for (int ni = 0; ni < 4; ni++) {
            const int lc = cl[ni];
            const int gj = tileJ + clocv[ni];
            float pmin =  INFINITY;
            float nmax = -INFINITY;
            #pragma unroll
            for (int mi = 0; mi < 4; mi++) {
                #pragma unroll
                for (int reg = 0; reg < 4; reg++) {
                    const float g = acc[mi][ni][reg];
                    const bool same = (rl[mi * 4 + reg] == lc);
                    if (same) pmin = fminf(pmin, g);
                    else      nmax = fmaxf(nmax, g);
                }
            }
            pmin = fminf(pmin, __shfl_xor(pmin, 16));
            pmin = fminf(pmin, __shfl_xor(pmin, 32));
            nmax = fmaxf(nmax, __shfl_xor(nmax, 16));
            nmax = fmaxf(nmax, __shfl_xor(nmax, 32));
            if (quad == 0) {
                if (pmin <  INFINITY) atomicMin(&posArr[gj], enc(pmin));
                if (nmax > -INFINITY) atomicMax(&negArr[gj], enc(nmax));
            }
        }
    }
}

// ---- kernel 3: per-row loss + mean over valid rows ----
__global__ void tl_final(const unsigned* __restrict__ posArr,
                         const unsigned* __restrict__ negArr,
                         float* __restrict__ out) {
    const int tid = threadIdx.x; // 1024 threads, 4 rows each, single pass
    uint4 pe4 = ((const uint4*)posArr)[tid];
    uint4 ne4 = ((const uint4*)negArr)[tid];
    unsigned pes[4] = {pe4.x, pe4.y, pe4.z, pe4.w};
    unsigned nes[4] = {ne4.x, ne4.y, ne4.z, ne4.w};
    float sum = 0.0f;
    int   count = 0;
    #pragma unroll
    for (int j = 0; j < 4; j++) {
        const bool valid = (pes[j] != POS_INIT) && (nes[j] != NEG_INIT);
        const float dap = sqrtf(fmaxf(2.0f - 2.0f * dec(pes[j]), 0.0f));
        const float dan = sqrtf(fmaxf(2.0f - 2.0f * dec(nes[j]), 0.0f));
        const float per = fmaxf(dap - dan + MARGIN, 0.0f);
        if (valid) { sum += per; count += 1; }
    }
    #pragma unroll
    for (int m = 32; m >= 1; m >>= 1) {
        sum   += __shfl_xor(sum, m);
        count += __shfl_xor(count, m);
    }
    __shared__ float ssum[16];
    __shared__ int   scnt[16];
    const int wave = tid >> 6, lane = tid & 63;
    if (lane == 0) { ssum[wave] = sum; scnt[wave] = count; }
    __syncthreads();
    if (tid == 0) {
        float s = 0.0f; int c = 0;
        #pragma unroll
        for (int w = 0; w < 16; w++) { s += ssum[w]; c += scnt[w]; }
        out[0] = (c > 0) ? (s / (float)c) : 0.0f;
    }
}

extern "C" void kernel_launch(void* const* d_in, const int* in_sizes, int n_in,
                              void* d_out, int out_size, void* d_ws, size_t ws_size,
                              hipStream_t stream) {
    const float* E      = (const float*)d_in[0];
    const int*   labels = (const int*)d_in[1];
    float*       out    = (float*)d_out;

    char* ws = (char*)d_ws;
    __hip_bfloat16* Ebf   = (__hip_bfloat16*)ws;                       // 4 MB
    unsigned* posArr      = (unsigned*)(ws + (size_t)NROW * DIM * 2);  // 16 KB
    unsigned* negArr      = posArr + NROW;                             // 16 KB

    tl_norm<<<NROW / 16, 256, 0, stream>>>(E, Ebf, posArr, negArr);
    tl_gram<<<NPAIR, 256, 0, stream>>>(Ebf, labels, posArr, negArr);
    tl_final<<<1, 1024, 0, stream>>>(posArr, negArr, out);
}

// Round 10
// 93.004 us; speedup vs baseline: 1.0544x; 1.0013x over previous
//
#include <hip/hip_runtime.h>
#include <hip/hip_bf16.h>
#include <stdint.h>

// BatchHardTripletLoss: N=4096, D=512, C=128, margin=0.3
// hardest-pos = min gram (same label, j!=i), hardest-neg = max gram (diff label).
// Gram symmetric => upper-triangular 128x128 tiles (528 blocks).
//
// R10 = R2 frozen (best measured: 89.2us; gram ~28.7us — seven alternative
// gram structures R5-R9 all plateaued 28-42us => treat as floor) + ONE change:
// tl_final fused into tl_gram via done-counter WITHOUT R3's per-block
// __threadfence (that fence = agent release = L2 writeback x528 => 130us).
// Correctness without fence: all communicated values are device-scope ATOMICS
// (executed at the coherent point). Each wave drains its own atomics with
// s_waitcnt vmcnt(0) (ACKed at coherent point), __syncthreads, then tid0 does
// a RELAXED agent fetch_add on doneCnt; the last block reads pos/neg with
// relaxed agent atomic loads (bypass local caches). No wait-loop => no
// deadlock mode. Saves one kernel launch + gap + inter-kernel cache ops.
//
// Ebf swizzled layout (16B units): off16(row, kchunk) = (kchunk/4)*16384
//   + (row/16)*64 + (kchunk&3)*16 + (row&15)
// => MFMA fragment load (16 rows x 32 k) = one contiguous 1KB wave load.

#define NROW 4096
#define DIM  512
#define MARGIN 0.3f
#define BT 128
#define NTILE (NROW / BT)                 // 32
#define NPAIR (NTILE * (NTILE + 1) / 2)   // 528
#define POS_INIT 0xFFFFFFFFu
#define NEG_INIT 0u

typedef __attribute__((ext_vector_type(8))) __bf16 bf16x8;
typedef __attribute__((ext_vector_type(4))) float  f32x4;
typedef __attribute__((ext_vector_type(8))) unsigned short u16x8;

// monotone float<->uint: order-preserving for atomicMin/Max on unsigned.
// enc(finite f) never equals POS_INIT (needs NaN) nor NEG_INIT (needs -NaN),
// so the init sentinels double as "no positive/negative seen" flags.
__device__ __forceinline__ unsigned enc(float f) {
    unsigned u = __float_as_uint(f);
    return (u & 0x80000000u) ? ~u : (u | 0x80000000u);
}
__device__ __forceinline__ float dec(unsigned e) {
    return (e & 0x80000000u) ? __uint_as_float(e & 0x7fffffffu)
                             : __uint_as_float(~e);
}

__device__ __forceinline__ unsigned short f2bf(float f) {
    __hip_bfloat16 h = __float2bfloat16(f);
    return *reinterpret_cast<unsigned short*>(&h);
}

// ---- kernel 1: L2-normalize rows -> bf16 swizzled layout, + init arrays ----
// one wave per row; 4 waves/block; 1024 blocks. (R2's norm, verbatim, + doneCnt
// init.) First 16 blocks init pos/neg sentinels; block 16 zeroes doneCnt.
__global__ void tl_norm(const float* __restrict__ E,
                        __hip_bfloat16* __restrict__ Ebf,
                        unsigned* __restrict__ posArr,
                        unsigned* __restrict__ negArr,
                        unsigned* __restrict__ doneCnt) {
    if (blockIdx.x < 16) {
        int t = blockIdx.x * 256 + threadIdx.x;   // covers 4096
        posArr[t] = POS_INIT;
        negArr[t] = NEG_INIT;
    }
    if (blockIdx.x == 16 && threadIdx.x == 0) *doneCnt = 0;

    int wave = threadIdx.x >> 6;
    int lane = threadIdx.x & 63;
    int row  = blockIdx.x * 4 + wave;

    // lane l owns kchunk l = 8 consecutive floats (bytes 32l..32l+31).
    const float4* src = (const float4*)(E + (size_t)row * DIM);
    float4 v0 = src[2 * lane];
    float4 v1 = src[2 * lane + 1];
    float ss = v0.x*v0.x + v0.y*v0.y + v0.z*v0.z + v0.w*v0.w
             + v1.x*v1.x + v1.y*v1.y + v1.z*v1.z + v1.w*v1.w;
    #pragma unroll
    for (int m = 32; m >= 1; m >>= 1) ss += __shfl_xor(ss, m);
    float inv = 1.0f / fmaxf(sqrtf(ss), 1e-12f);

    u16x8 o;
    o[0] = f2bf(v0.x * inv); o[1] = f2bf(v0.y * inv);
    o[2] = f2bf(v0.z * inv); o[3] = f2bf(v0.w * inv);
    o[4] = f2bf(v1.x * inv); o[5] = f2bf(v1.y * inv);
    o[6] = f2bf(v1.z * inv); o[7] = f2bf(v1.w * inv);

    // swizzled store: lane l is kchunk l of this row
    const int ktile = lane >> 2, c_in = lane & 3;
    const int rtile = row >> 4,  r_in = row & 15;
    const size_t off16 = (size_t)ktile * 16384 + (size_t)rtile * 64
                       + (size_t)c_in * 16 + r_in;       // in 16B units
    ((u16x8*)Ebf)[off16] = o;
}

// ---- kernel 2: upper-tri bf16 MFMA Gram (R2 frozen) + fused final ----
// 528 blocks x 256 thr (4 waves, 2x2; wave-tile 64x64). Direct-from-L2
// swizzled fragment loads, ring-4 source-level prefetch, zero K-loop barriers.
__global__ void __launch_bounds__(256, 2)
tl_gram(const __hip_bfloat16* __restrict__ Ebf,
        const int* __restrict__ labels,
        unsigned* __restrict__ posArr,
        unsigned* __restrict__ negArr,
        unsigned* __restrict__ doneCnt,
        float* __restrict__ out) {
    __shared__ int rowLab[BT];
    __shared__ int colLab[BT];

    // bijective XCD swizzle: 528 = 8 * 66; consecutive swz ids (same bi ->
    // shared A panel) land on the same XCD's L2.
    int bid = blockIdx.x;
    int t = (bid & 7) * (NPAIR / 8) + (bid >> 3);

    // triangular decode: t -> (bi, bj) with bi <= bj
    int bi = 0, rowlen = NTILE;
    while (t >= rowlen) { t -= rowlen; rowlen--; bi++; }
    const int bj = bi + t;

    const int tid  = threadIdx.x;
    const int wave = tid >> 6;
    const int lane = tid & 63;
    const int quad = lane >> 4;
    const int l16  = lane & 15;
    const int wr   = wave >> 1;   // 0..1: rows wr*64..+63
    const int wc   = wave & 1;    // 0..1: cols wc*64..+63
    const int tileI = bi * BT;
    const int tileJ = bj * BT;
    const bool diag = (bi == bj);

    if (tid < BT) rowLab[tid] = labels[tileI + tid];
    else          colLab[tid - BT] = labels[tileJ + (tid - BT)];
    __syncthreads();

    // swizzled fragment base: frag(rowbase,kk) at 16B-unit offset
    //   kk*16384 + (rowbase/16)*64 + lane      (fully lane-contiguous 1KB)
    const bf16x8* Ev = (const bf16x8*)Ebf;
    const bf16x8* Ea = Ev + ((tileI + wr * 64) >> 4) * 64 + lane;
    const bf16x8* Eb = Ev + ((tileJ + wc * 64) >> 4) * 64 + lane;

    f32x4 acc[4][4] = {};
    bf16x8 a[4][4], b[4][4];   // ring slot x frag — all indices compile-time

    #pragma unroll
    for (int p = 0; p < 3; ++p) {
        #pragma unroll
        for (int i = 0; i < 4; i++) {
            a[p][i] = Ea[p * 16384 + i * 64];
            b[p][i] = Eb[p * 16384 + i * 64];
        }
    }
    #pragma unroll
    for (int kk = 0; kk < 16; ++kk) {      // 16 K-steps of 32
        const int cur = kk & 3;
        if (kk + 3 < 16) {
            const int nx = (kk + 3) & 3;
            #pragma unroll
            for (int i = 0; i < 4; i++) {
                a[nx][i] = Ea[(kk + 3) * 16384 + i * 64];
                b[nx][i] = Eb[(kk + 3) * 16384 + i * 64];
            }
        }
        #pragma unroll
        for (int mi = 0; mi < 4; mi++)
            #pragma unroll
            for (int ni = 0; ni < 4; ni++)
                acc[mi][ni] = __builtin_amdgcn_mfma_f32_16x16x32_bf16(
                    a[cur][mi], b[cur][ni], acc[mi][ni], 0, 0, 0);
    }

    // C/D layout: col = wc*64+ni*16+l16 (lane), row = wr*64+mi*16+quad*4+reg
    int rl[16], cl[4], clocv[4];
    #pragma unroll
    for (int mi = 0; mi < 4; mi++)
        #pragma unroll
        for (int reg = 0; reg < 4; reg++)
            rl[mi * 4 + reg] = rowLab[wr * 64 + mi * 16 + quad * 4 + reg];
    #pragma unroll
    for (int ni = 0; ni < 4; ni++) {
        clocv[ni] = wc * 64 + ni * 16 + l16;
        cl[ni] = colLab[clocv[ni]];
    }

    // ---- row pass: reduce over this wave's 64 cols, rows of tileI ----
    #pragma unroll
    for (int mi = 0; mi < 4; mi++) {
        #pragma unroll
        for (int reg = 0; reg < 4; reg++) {
            const int rloc = wr * 64 + mi * 16 + quad * 4 + reg;
            const int lr   = rl[mi * 4 + reg];
            const int gi   = tileI + rloc;
            float pmin =  INFINITY;
            float nmax = -INFINITY;
            #pragma unroll
            for (int ni = 0; ni < 4; ni++) {
                const int gj  = tileJ + clocv[ni];
                const float g = acc[mi][ni][reg];
                const bool same = (lr == cl[ni]);
                if (same && gi != gj) pmin = fminf(pmin, g);
                if (!same)            nmax = fmaxf(nmax, g);
            }
            #pragma unroll
            for (int m = 1; m < 16; m <<= 1) {
                pmin = fminf(pmin, __shfl_xor(pmin, m));
                nmax = fmaxf(nmax, __shfl_xor(nmax, m));
            }
            if (l16 == 0) {
                if (pmin <  INFINITY) atomicMin(&posArr[gi], enc(pmin));
                if (nmax > -INFINITY) atomicMax(&negArr[gi], enc(nmax));
            }
        }
    }

    // ---- col pass (off-diag only): reduce over this wave's 64 rows ----
    if (!diag) {
        #pragma unroll
        for (int ni = 0; ni < 4; ni++) {
            const int lc = cl[ni];
            const int gj = tileJ + clocv[ni];
            float pmin =  INFINITY;
            float nmax = -INFINITY;
            #pragma unroll
            for (int mi = 0; mi < 4; mi++) {
                #pragma unroll
                for (int reg = 0; reg < 4; reg++) {
                    const float g = acc[mi][ni][reg];
                    const bool same = (rl[mi * 4 + reg] == lc);
                    if (same) pmin = fminf(pmin, g);
                    else      nmax = fmaxf(nmax, g);
                }
            }
            pmin = fminf(pmin, __shfl_xor(pmin, 16));
            pmin = fminf(pmin, __shfl_xor(pmin, 32));
            nmax = fmaxf(nmax, __shfl_xor(nmax, 16));
            nmax = fmaxf(nmax, __shfl_xor(nmax, 32));
            if (quad == 0) {
                if (pmin <  INFINITY) atomicMin(&posArr[gj], enc(pmin));
                if (nmax > -INFINITY) atomicMax(&negArr[gj], enc(nmax));
            }
        }
    }

    // ---- fused final: last block to arrive reduces the loss ----
    // Per-wave vmcnt(0): this wave's device-scope atomics are ACKed at the
    // coherent point (cheap; NO cache writeback — the R3 killer is absent).
    asm volatile("s_waitcnt vmcnt(0)" ::: "memory");
    __shared__ unsigned sOld;
    __syncthreads();                       // all waves drained
    if (tid == 0)
        sOld = __hip_atomic_fetch_add(doneCnt, 1u, __ATOMIC_RELAXED,
                                      __HIP_MEMORY_SCOPE_AGENT);
    __syncthreads();
    if (sOld == NPAIR - 1) {
        float sum = 0.0f;
        int   cnt = 0;
        for (int i = tid; i < NROW; i += 256) {
            const unsigned pe = __hip_atomic_load(&posArr[i], __ATOMIC_RELAXED,
                                                  __HIP_MEMORY_SCOPE_AGENT);
            const unsigned ne = __hip_atomic_load(&negArr[i], __ATOMIC_RELAXED,
                                                  __HIP_MEMORY_SCOPE_AGENT);
            const bool valid = (pe != POS_INIT) && (ne != NEG_INIT);
            const float dap = sqrtf(fmaxf(2.0f - 2.0f * dec(pe), 0.0f));
            const float dan = sqrtf(fmaxf(2.0f - 2.0f * dec(ne), 0.0f));
            const float per = fmaxf(dap - dan + MARGIN, 0.0f);
            if (valid) { sum += per; cnt += 1; }
        }
        #pragma unroll
        for (int m = 32; m >= 1; m >>= 1) {
            sum += __shfl_xor(sum, m);
            cnt += __shfl_xor(cnt, m);
        }
        __shared__ float ssum[4];
        __shared__ int   scnt[4];
        if (lane == 0) { ssum[wave] = sum; scnt[wave] = cnt; }
        __syncthreads();
        if (tid == 0) {
            float s = ssum[0] + ssum[1] + ssum[2] + ssum[3];
            int   c = scnt[0] + scnt[1] + scnt[2] + scnt[3];
            out[0] = (c > 0) ? (s / (float)c) : 0.0f;
        }
    }
}

extern "C" void kernel_launch(void* const* d_in, const int* in_sizes, int n_in,
                              void* d_out, int out_size, void* d_ws, size_t ws_size,
                              hipStream_t stream) {
    const float* E      = (const float*)d_in[0];
    const int*   labels = (const int*)d_in[1];
    float*       out    = (float*)d_out;

    char* ws = (char*)d_ws;
    __hip_bfloat16* Ebf   = (__hip_bfloat16*)ws;                       // 4 MB
    unsigned* posArr      = (unsigned*)(ws + (size_t)NROW * DIM * 2);  // 16 KB
    unsigned* negArr      = posArr + NROW;                             // 16 KB
    unsigned* doneCnt     = negArr + NROW;                             // 4 B

    tl_norm<<<NROW / 4, 256, 0, stream>>>(E, Ebf, posArr, negArr, doneCnt);
    tl_gram<<<NPAIR, 256, 0, stream>>>(Ebf, labels, posArr, negArr, doneCnt, out);
}

// Round 11
// 88.176 us; speedup vs baseline: 1.1121x; 1.0548x over previous
//
#include <hip/hip_runtime.h>
#include <hip/hip_bf16.h>
#include <stdint.h>

// BatchHardTripletLoss: N=4096, D=512, C=128, margin=0.3
// hardest-pos = min gram (same label, j!=i), hardest-neg = max gram (diff label).
// Gram symmetric => upper-triangular 128x128 tiles (528 blocks).
//
// FINAL (R11) = R2 verbatim, the best harness-verified configuration (89.2us).
// Session evidence: seven structurally distinct gram kernels (direct-L2 ring,
// +occupancy, +sched_barrier, 2-phase LDS, counted-vmcnt regs, counted-vmcnt
// LDS ring, fused-final) plateau at 28-42us for the Gram stage; R2's
// free-running direct-from-L2 swizzled-fragment loads are the floor of that
// family. Total ~= 43.8us harness ws-poison fill (untouchable) + ~28.7us gram
// + ~16us norm/final/gaps (fusion-proven incompressible, R10).
//
// Ebf swizzled layout (16B units): off16(row, kchunk) = (kchunk/4)*16384
//   + (row/16)*64 + (kchunk&3)*16 + (row&15)
// => MFMA fragment load (16 rows x 32 k) = one contiguous 1KB wave load.

#define NROW 4096
#define DIM  512
#define MARGIN 0.3f
#define BT 128
#define NTILE (NROW / BT)                 // 32
#define NPAIR (NTILE * (NTILE + 1) / 2)   // 528
#define POS_INIT 0xFFFFFFFFu
#define NEG_INIT 0u

typedef __attribute__((ext_vector_type(8))) __bf16 bf16x8;
typedef __attribute__((ext_vector_type(4))) float  f32x4;
typedef __attribute__((ext_vector_type(8))) unsigned short u16x8;

// monotone float<->uint: order-preserving for atomicMin/Max on unsigned.
// enc(finite f) can never equal POS_INIT (needs NaN) nor NEG_INIT (needs -NaN),
// so the init sentinels double as "no positive/negative seen" flags.
__device__ __forceinline__ unsigned enc(float f) {
    unsigned u = __float_as_uint(f);
    return (u & 0x80000000u) ? ~u : (u | 0x80000000u);
}
__device__ __forceinline__ float dec(unsigned e) {
    return (e & 0x80000000u) ? __uint_as_float(e & 0x7fffffffu)
                             : __uint_as_float(~e);
}

__device__ __forceinline__ unsigned short f2bf(float f) {
    __hip_bfloat16 h = __float2bfloat16(f);
    return *reinterpret_cast<unsigned short*>(&h);
}

// ---- kernel 1: L2-normalize rows -> bf16 in swizzled layout, + init arrays ----
// one wave per row; 4 waves/block; 1024 blocks (first 16 also init pos/neg)
__global__ void tl_norm(const float* __restrict__ E,
                        __hip_bfloat16* __restrict__ Ebf,
                        unsigned* __restrict__ posArr,
                        unsigned* __restrict__ negArr) {
    if (blockIdx.x < 16) {
        int t = blockIdx.x * 256 + threadIdx.x;   // covers 4096
        posArr[t] = POS_INIT;
        negArr[t] = NEG_INIT;
    }
    int wave = threadIdx.x >> 6;
    int lane = threadIdx.x & 63;
    int row  = blockIdx.x * 4 + wave;

    // lane l owns kchunk l = 8 consecutive floats (bytes 32l..32l+31).
    const float4* src = (const float4*)(E + (size_t)row * DIM);
    float4 v0 = src[2 * lane];
    float4 v1 = src[2 * lane + 1];
    float ss = v0.x*v0.x + v0.y*v0.y + v0.z*v0.z + v0.w*v0.w
             + v1.x*v1.x + v1.y*v1.y + v1.z*v1.z + v1.w*v1.w;
    #pragma unroll
    for (int m = 32; m >= 1; m >>= 1) ss += __shfl_xor(ss, m);
    float inv = 1.0f / fmaxf(sqrtf(ss), 1e-12f);

    u16x8 o;
    o[0] = f2bf(v0.x * inv); o[1] = f2bf(v0.y * inv);
    o[2] = f2bf(v0.z * inv); o[3] = f2bf(v0.w * inv);
    o[4] = f2bf(v1.x * inv); o[5] = f2bf(v1.y * inv);
    o[6] = f2bf(v1.z * inv); o[7] = f2bf(v1.w * inv);

    // swizzled store: lane l is kchunk l of this row
    const int ktile = lane >> 2, c_in = lane & 3;
    const int rtile = row >> 4,  r_in = row & 15;
    const size_t off16 = (size_t)ktile * 16384 + (size_t)rtile * 64
                       + (size_t)c_in * 16 + r_in;       // in 16B units
    ((u16x8*)Ebf)[off16] = o;
}

// ---- kernel 2: upper-triangular bf16 MFMA Gram, swizzled direct-L2 frags ----
// 128x128 tile per block, 4 waves in 2x2, each wave 4x4 of 16x16x32 MFMA.
// No LDS staging, no barriers in the K-loop: 4-deep register prefetch ring.
__global__ void __launch_bounds__(256, 2)
tl_gram(const __hip_bfloat16* __restrict__ Ebf,
        const int* __restrict__ labels,
        unsigned* __restrict__ posArr,
        unsigned* __restrict__ negArr) {
    __shared__ int rowLab[BT];
    __shared__ int colLab[BT];

    // bijective XCD swizzle: 528 blocks, 8 XCDs, 66 consecutive logical
    // blocks per XCD -> consecutive bi (shared A panel) co-resident in one L2.
    int bid = blockIdx.x;
    int t = (bid & 7) * (NPAIR / 8) + (bid >> 3);

    // triangular decode: t -> (bi, bj) with bi <= bj
    int bi = 0, rowlen = NTILE;
    while (t >= rowlen) { t -= rowlen; rowlen--; bi++; }
    const int bj = bi + t;

    const int tid  = threadIdx.x;
    const int wave = tid >> 6;
    const int lane = tid & 63;
    const int quad = lane >> 4;
    const int l16  = lane & 15;
    const int wr   = wave >> 1;   // wave row (0..1): rows wr*64..+63
    const int wc   = wave & 1;    // wave col (0..1): cols wc*64..+63
    const int tileI = bi * BT;
    const int tileJ = bj * BT;
    const bool diag = (bi == bj);

    if (tid < BT) rowLab[tid] = labels[tileI + tid];
    else          colLab[tid - BT] = labels[tileJ + (tid - BT)];
    __syncthreads();   // the only block-wide sync

    // swizzled layout: frag(rowbase, kk) at 16B-unit offset
    //   kk*16384 + (rowbase/16)*64 + lane      (fully lane-contiguous 1KB)
    const bf16x8* Ev = (const bf16x8*)Ebf;
    const bf16x8* Ea = Ev + ((tileI + wr * 64) >> 4) * 64 + lane;
    const bf16x8* Eb = Ev + ((tileJ + wc * 64) >> 4) * 64 + lane;

    f32x4 acc[4][4] = {};
    bf16x8 a[4][4], b[4][4];   // [ring slot][frag] — all indices compile-time

    #pragma unroll
    for (int p = 0; p < 3; ++p) {
        #pragma unroll
        for (int i = 0; i < 4; i++) {
            a[p][i] = Ea[p * 16384 + i * 64];
            b[p][i] = Eb[p * 16384 + i * 64];
        }
    }
    #pragma unroll
    for (int kk = 0; kk < 16; ++kk) {      // 16 K-steps of 32
        const int cur = kk & 3;
        if (kk + 3 < 16) {
            const int nxt = (kk + 3) & 3;
            #pragma unroll
            for (int i = 0; i < 4; i++) {
                a[nxt][i] = Ea[(kk + 3) * 16384 + i * 64];
                b[nxt][i] = Eb[(kk + 3) * 16384 + i * 64];
            }
        }
        #pragma unroll
        for (int mi = 0; mi < 4; mi++)
            #pragma unroll
            for (int ni = 0; ni < 4; ni++)
                acc[mi][ni] = __builtin_amdgcn_mfma_f32_16x16x32_bf16(
                    a[cur][mi], b[cur][ni], acc[mi][ni], 0, 0, 0);
    }

    // C/D layout: col = wc*64+ni*16+l16 (lane), row = wr*64+mi*16+quad*4+reg
    int rl[16], cl[4], clocv[4];
    #pragma unroll
    for (int mi = 0; mi < 4; mi++)
        #pragma unroll
        for (int reg = 0; reg < 4; reg++)
            rl[mi * 4 + reg] = rowLab[wr * 64 + mi * 16 + quad * 4 + reg];
    #pragma unroll
    for (int ni = 0; ni < 4; ni++) {
        clocv[ni] = wc * 64 + ni * 16 + l16;
        cl[ni] = colLab[clocv[ni]];
    }

    // ---- row pass: reduce over this tile's columns, for rows of tileI ----
    #pragma unroll
    for (int mi = 0; mi < 4; mi++) {
        #pragma unroll
        for (int reg = 0; reg < 4; reg++) {
            const int rloc = wr * 64 + mi * 16 + quad * 4 + reg;
            const int lr   = rl[mi * 4 + reg];
            const int gi   = tileI + rloc;
            float pmin =  INFINITY;
            float nmax = -INFINITY;
            #pragma unroll
            for (int ni = 0; ni < 4; ni++) {
                const int gj  = tileJ + clocv[ni];
                const float g = acc[mi][ni][reg];
                const bool same = (lr == cl[ni]);
                if (same && gi != gj) pmin = fminf(pmin, g);
                if (!same)            nmax = fmaxf(nmax, g);
            }
            #pragma unroll
            for (int m = 1; m < 16; m <<= 1) {
                pmin = fminf(pmin, __shfl_xor(pmin, m));
                nmax = fmaxf(nmax, __shfl_xor(nmax, m));
            }
            if (l16 == 0) {
                if (pmin <  INFINITY) atomicMin(&posArr[gi], enc(pmin));
                if (nmax > -INFINITY) atomicMax(&negArr[gi], enc(nmax));
            }
        }
    }

    // ---- col pass (off-diag only): reduce over rows, for rows of tileJ ----
    if (!diag) {
        #pragma unroll
        for (int ni = 0; ni < 4; ni++) {
            const int lc = cl[ni];
            const int gj = tileJ + clocv[ni];
            float pmin =  INFINITY;
            float nmax = -INFINITY;
            #pragma unroll
            for (int mi = 0; mi < 4; mi++) {
                #pragma unroll
                for (int reg = 0; reg < 4; reg++) {
                    const float g = acc[mi][ni][reg];
                    const bool same = (rl[mi * 4 + reg] == lc);
                    if (same) pmin = fminf(pmin, g);
                    else      nmax = fmaxf(nmax, g);
                }
            }
            pmin = fminf(pmin, __shfl_xor(pmin, 16));
            pmin = fminf(pmin, __shfl_xor(pmin, 32));
            nmax = fmaxf(nmax, __shfl_xor(nmax, 16));
            nmax = fmaxf(nmax, __shfl_xor(nmax, 32));
            if (quad == 0) {
                if (pmin <  INFINITY) atomicMin(&posArr[gj], enc(pmin));
                if (nmax > -INFINITY) atomicMax(&negArr[gj], enc(nmax));
            }
        }
    }
}

// ---- kernel 3: per-row loss + mean over valid rows ----
__global__ void tl_final(const unsigned* __restrict__ posArr,
                         const unsigned* __restrict__ negArr,
                         float* __restrict__ out) {
    const int tid = threadIdx.x; // 1024 threads, 4 rows each, single pass
    uint4 pe4 = ((const uint4*)posArr)[tid];
    uint4 ne4 = ((const uint4*)negArr)[tid];
    unsigned pes[4] = {pe4.x, pe4.y, pe4.z, pe4.w};
    unsigned nes[4] = {ne4.x, ne4.y, ne4.z, ne4.w};
    float sum = 0.0f;
    int   count = 0;
    #pragma unroll
    for (int j = 0; j < 4; j++) {
        const bool valid = (pes[j] != POS_INIT) && (nes[j] != NEG_INIT);
        const float dap = sqrtf(fmaxf(2.0f - 2.0f * dec(pes[j]), 0.0f));
        const float dan = sqrtf(fmaxf(2.0f - 2.0f * dec(nes[j]), 0.0f));
        const float per = fmaxf(dap - dan + MARGIN, 0.0f);
        if (valid) { sum += per; count += 1; }
    }
    #pragma unroll
    for (int m = 32; m >= 1; m >>= 1) {
        sum   += __shfl_xor(sum, m);
        count += __shfl_xor(count, m);
    }
    __shared__ float ssum[16];
    __shared__ int   scnt[16];
    const int wave = tid >> 6, lane = tid & 63;
    if (lane == 0) { ssum[wave] = sum; scnt[wave] = count; }
    __syncthreads();
    if (tid == 0) {
        float s = 0.0f; int c = 0;
        #pragma unroll
        for (int w = 0; w < 16; w++) { s += ssum[w]; c += scnt[w]; }
        out[0] = (c > 0) ? (s / (float)c) : 0.0f;
    }
}

extern "C" void kernel_launch(void* const* d_in, const int* in_sizes, int n_in,
                              void* d_out, int out_size, void* d_ws, size_t ws_size,
                              hipStream_t stream) {
    const float* E      = (const float*)d_in[0];
    const int*   labels = (const int*)d_in[1];
    float*       out    = (float*)d_out;

    char* ws = (char*)d_ws;
    __hip_bfloat16* Ebf   = (__hip_bfloat16*)ws;                       // 4 MB
    unsigned* posArr      = (unsigned*)(ws + (size_t)NROW * DIM * 2);  // 16 KB
    unsigned* negArr      = posArr + NROW;                             // 16 KB

    tl_norm<<<NROW / 4, 256, 0, stream>>>(E, Ebf, posArr, negArr);
    tl_gram<<<NPAIR, 256, 0, stream>>>(Ebf, labels, posArr, negArr);
    tl_final<<<1, 1024, 0, stream>>>(posArr, negArr, out);
}